// Round 1
// baseline (114.523 us; speedup 1.0000x reference)
//
#include <hip/hip_runtime.h>
#include <hip/hip_bf16.h>

typedef __bf16 bf16;
typedef __attribute__((ext_vector_type(8))) __bf16 bf16x8;
typedef __attribute__((ext_vector_type(4))) float floatx4;

#define PP 16
#define PPW 9
#define CFEAT 432      // C*P*PW = 3*16*9
#define EDIM 768
#define KDIM 768       // C*P*P = 3*256
#define NPAT 196
#define NBATCH 128
#define LDT 40         // padded LDS row stride in bf16 elems (80 B = 20 banks)

// ---------------------------------------------------------------------------
// Kernel 1: fold rfft2(ortho).real * fwh * fww into proj_w -> W_eff (bf16)
// W_eff[e][c*256 + h*16 + w] =
//   (1/16) * sum_{u,v} proj_w[e][c*144+u*9+v] * fwh[u]*fww[v]*cos(2pi(uh+vw)/16)
// grid: 768*3 blocks of 256 threads; block = (e, c); thread = (h, w)
// ---------------------------------------------------------------------------
__global__ __launch_bounds__(256) void build_w_kernel(
    const float* __restrict__ pw, const float* __restrict__ fwh,
    const float* __restrict__ fww, bf16* __restrict__ Wb) {
  __shared__ float s_pw[144];
  __shared__ float s_fh[16];
  __shared__ float s_fw[9];
  __shared__ float s_cos[16];
  const int blk = blockIdx.x;
  const int e = blk / 3;
  const int c = blk % 3;
  const int t = threadIdx.x;
  if (t < 144) s_pw[t] = pw[e * CFEAT + c * 144 + t];
  if (t < 16) {
    s_fh[t] = fwh[t];
    s_cos[t] = cosf((float)t * 0.39269908169872414f);  // 2*pi/16
  }
  if (t < 9) s_fw[t] = fww[t];
  __syncthreads();
  const int h = t >> 4, w = t & 15;
  float acc = 0.f;
#pragma unroll
  for (int u = 0; u < 16; ++u) {
    const float fh = s_fh[u];
    const int uh = (u * h) & 15;
#pragma unroll
    for (int v = 0; v < 9; ++v) {
      acc += s_pw[u * 9 + v] * s_fw[v] * s_cos[(uh + v * w) & 15] * fh;
    }
  }
  Wb[e * KDIM + c * 256 + t] = (bf16)(acc * 0.0625f);
}

// ---------------------------------------------------------------------------
// Kernel 2: GEMM  C[row=b*196+n][e] = sum_k A[row][k] * W_eff[e][k]
// A gathered on the fly from x (patch unfold), fp32 -> bf16.
// 128x128 tile, 4 waves of 64x64, BK=32, mfma_f32_16x16x32_bf16.
// Epilogue adds proj_b + pos_emb and scatters to out[b][1+n][e].
// ---------------------------------------------------------------------------
__global__ __launch_bounds__(256) void gemm_kernel(
    const float* __restrict__ x, const bf16* __restrict__ Wb,
    const float* __restrict__ pb, const float* __restrict__ pos,
    float* __restrict__ out) {
  __shared__ __align__(16) bf16 sA[128 * LDT];
  __shared__ __align__(16) bf16 sB[128 * LDT];

  const int nt = blockIdx.x;  // 0..5   (E tiles)
  const int mt = blockIdx.y;  // 0..195 (row tiles)
  const int t = threadIdx.x;
  const int l = t & 63;
  const int wv = t >> 6;
  const int wm = wv >> 1, wn = wv & 1;

  // staging assignment: thread -> (row, k-half)
  const int sr = t >> 1;    // 0..127
  const int half = t & 1;   // 0/1 -> k offset 0/16

  const unsigned R = mt * 128u + sr;
  const unsigned bb = R / 196u;
  const unsigned np = R - bb * 196u;
  const unsigned ph = np / 14u;
  const unsigned pwc = np - ph * 14u;
  const int eRow = nt * 128 + sr;

  floatx4 acc[4][4];
#pragma unroll
  for (int i = 0; i < 4; ++i)
#pragma unroll
    for (int j = 0; j < 4; ++j) acc[i][j] = (floatx4){0.f, 0.f, 0.f, 0.f};

  const int lk = (l >> 4) << 3;  // 0,8,16,24
  const int lr = l & 15;

  for (int kt = 0; kt < 24; ++kt) {
    const int kg = kt * 32 + half * 16;
    const int c = kg >> 8;
    const int hh = (kg & 255) >> 4;
    // A source: x[bb][c][ph*16+hh][pwc*16 .. +16]  (16 contiguous floats)
    const float* src =
        x + (((size_t)(bb * 3u + c) * 224u + ph * 16u + hh) * 224u + pwc * 16u);
    const float4 f0 = *reinterpret_cast<const float4*>(src + 0);
    const float4 f1 = *reinterpret_cast<const float4*>(src + 4);
    const float4 f2 = *reinterpret_cast<const float4*>(src + 8);
    const float4 f3 = *reinterpret_cast<const float4*>(src + 12);
    bf16x8 a0, a1;
    a0[0] = (bf16)f0.x; a0[1] = (bf16)f0.y; a0[2] = (bf16)f0.z; a0[3] = (bf16)f0.w;
    a0[4] = (bf16)f1.x; a0[5] = (bf16)f1.y; a0[6] = (bf16)f1.z; a0[7] = (bf16)f1.w;
    a1[0] = (bf16)f2.x; a1[1] = (bf16)f2.y; a1[2] = (bf16)f2.z; a1[3] = (bf16)f2.w;
    a1[4] = (bf16)f3.x; a1[5] = (bf16)f3.y; a1[6] = (bf16)f3.z; a1[7] = (bf16)f3.w;
    // B source: W_eff[eRow][kg .. +16] (32 contiguous bytes)
    const bf16x8 b0 =
        *reinterpret_cast<const bf16x8*>(Wb + (size_t)eRow * KDIM + kg);
    const bf16x8 b1 =
        *reinterpret_cast<const bf16x8*>(Wb + (size_t)eRow * KDIM + kg + 8);

    __syncthreads();  // previous iteration's reads complete
    *reinterpret_cast<bf16x8*>(&sA[sr * LDT + half * 16]) = a0;
    *reinterpret_cast<bf16x8*>(&sA[sr * LDT + half * 16 + 8]) = a1;
    *reinterpret_cast<bf16x8*>(&sB[sr * LDT + half * 16]) = b0;
    *reinterpret_cast<bf16x8*>(&sB[sr * LDT + half * 16 + 8]) = b1;
    __syncthreads();

    bf16x8 af[4], bfr[4];
#pragma unroll
    for (int mi = 0; mi < 4; ++mi)
      af[mi] = *reinterpret_cast<const bf16x8*>(
          &sA[(wm * 64 + mi * 16 + lr) * LDT + lk]);
#pragma unroll
    for (int ni = 0; ni < 4; ++ni)
      bfr[ni] = *reinterpret_cast<const bf16x8*>(
          &sB[(wn * 64 + ni * 16 + lr) * LDT + lk]);
#pragma unroll
    for (int mi = 0; mi < 4; ++mi)
#pragma unroll
      for (int ni = 0; ni < 4; ++ni)
        acc[mi][ni] = __builtin_amdgcn_mfma_f32_16x16x32_bf16(
            af[mi], bfr[ni], acc[mi][ni], 0, 0, 0);
  }

  // epilogue: out[b][1+n][e] = acc + proj_b[e] + pos_emb[1+n][e]
  float pbv[4];
#pragma unroll
  for (int ni = 0; ni < 4; ++ni)
    pbv[ni] = pb[nt * 128 + wn * 64 + ni * 16 + (l & 15)];

#pragma unroll
  for (int mi = 0; mi < 4; ++mi) {
#pragma unroll
    for (int j = 0; j < 4; ++j) {
      const unsigned m = wm * 64 + mi * 16 + ((l >> 4) << 2) + j;
      const unsigned Rr = mt * 128u + m;
      const unsigned b2 = Rr / 196u;
      const unsigned np2 = Rr - b2 * 196u;
      float* orow = out + ((size_t)b2 * 197 + 1 + np2) * 768;
      const float* prow = pos + (size_t)(1 + np2) * 768;
#pragma unroll
      for (int ni = 0; ni < 4; ++ni) {
        const int e = nt * 128 + wn * 64 + ni * 16 + (l & 15);
        orow[e] = acc[mi][ni][j] + pbv[ni] + prow[e];
      }
    }
  }
}

// ---------------------------------------------------------------------------
// Kernel 3: cls row  out[b][0][e] = cls[e] + pos_emb[0][e]
// ---------------------------------------------------------------------------
__global__ __launch_bounds__(256) void cls_kernel(
    const float* __restrict__ cls, const float* __restrict__ pos,
    float* __restrict__ out) {
  const int idx = blockIdx.x * 256 + threadIdx.x;  // < 128*768
  const int b = idx / 768;
  const int e = idx - b * 768;
  out[(size_t)b * 197 * 768 + e] = cls[e] + pos[e];
}

extern "C" void kernel_launch(void* const* d_in, const int* in_sizes, int n_in,
                              void* d_out, int out_size, void* d_ws,
                              size_t ws_size, hipStream_t stream) {
  const float* x = (const float*)d_in[0];
  const float* fwh = (const float*)d_in[1];
  const float* fww = (const float*)d_in[2];
  const float* proj_w = (const float*)d_in[3];
  const float* proj_b = (const float*)d_in[4];
  const float* cls = (const float*)d_in[5];
  const float* pos = (const float*)d_in[6];
  float* out = (float*)d_out;

  bf16* Wb = (bf16*)d_ws;  // 768*768*2 = 1.18 MB

  build_w_kernel<<<EDIM * 3, 256, 0, stream>>>(proj_w, fwh, fww, Wb);
  cls_kernel<<<(NBATCH * EDIM) / 256, 256, 0, stream>>>(cls, pos, out);
  gemm_kernel<<<dim3(6, 196), 256, 0, stream>>>(x, Wb, proj_b, pos, out);
}

// Round 2
// 99.151 us; speedup vs baseline: 1.1550x; 1.1550x over previous
//
#include <hip/hip_runtime.h>
#include <hip/hip_bf16.h>

typedef __bf16 bf16;
typedef __attribute__((ext_vector_type(8))) __bf16 bf16x8;
typedef __attribute__((ext_vector_type(4))) float floatx4;

#define PP 16
#define PPW 9
#define CFEAT 432      // C*P*PW = 3*16*9
#define EDIM 768
#define KDIM 768       // C*P*P = 3*256
#define NPAT 196
#define NBATCH 128
#define MROWS (NBATCH * NPAT)  // 25088
#define LDT 40         // fallback-path padded LDS stride

__device__ inline void gload16(const void* g, void* l) {
  __builtin_amdgcn_global_load_lds(
      (const __attribute__((address_space(1))) void*)g,
      (__attribute__((address_space(3))) void*)l, 16, 0, 0);
}

// ---------------------------------------------------------------------------
// Kernel 1: fold rfft2(ortho).real * fwh * fww into proj_w -> W_eff (bf16)
// W_eff[e][c*256 + h*16 + w] =
//   (1/16) * sum_{u,v} proj_w[e][c*144+u*9+v] * fwh[u]*fww[v]*cos(2pi(uh+vw)/16)
// ---------------------------------------------------------------------------
__global__ __launch_bounds__(256) void build_w_kernel(
    const float* __restrict__ pw, const float* __restrict__ fwh,
    const float* __restrict__ fww, bf16* __restrict__ Wb) {
  __shared__ float s_pw[144];
  __shared__ float s_fh[16];
  __shared__ float s_fw[9];
  __shared__ float s_cos[16];
  const int blk = blockIdx.x;
  const int e = blk / 3;
  const int c = blk % 3;
  const int t = threadIdx.x;
  if (t < 144) s_pw[t] = pw[e * CFEAT + c * 144 + t];
  if (t < 16) {
    s_fh[t] = fwh[t];
    s_cos[t] = cosf((float)t * 0.39269908169872414f);  // 2*pi/16
  }
  if (t < 9) s_fw[t] = fww[t];
  __syncthreads();
  const int h = t >> 4, w = t & 15;
  float acc = 0.f;
#pragma unroll
  for (int u = 0; u < 16; ++u) {
    const float fh = s_fh[u];
    const int uh = (u * h) & 15;
#pragma unroll
    for (int v = 0; v < 9; ++v) {
      acc += s_pw[u * 9 + v] * s_fw[v] * s_cos[(uh + v * w) & 15] * fh;
    }
  }
  Wb[e * KDIM + c * 256 + t] = (bf16)(acc * 0.0625f);
}

// ---------------------------------------------------------------------------
// Kernel 2: patch-unfold + fp32->bf16:  A[b*196+n][c*256+h2*16+w2] = x[b][c][h][w]
// Each thread: 8 contiguous floats -> 8 contiguous bf16 (same patch row-chunk).
// ---------------------------------------------------------------------------
__global__ __launch_bounds__(256) void unfold_kernel(
    const float* __restrict__ x, bf16* __restrict__ A) {
  const int i = blockIdx.x * 256 + threadIdx.x;  // < 2408448
  const int w8 = i % 28;
  const int tmp = i / 28;
  const int h = tmp % 224;
  const int tmp2 = tmp / 224;
  const int c = tmp2 % 3;
  const int b = tmp2 / 3;
  const float4 f0 = *reinterpret_cast<const float4*>(x + (size_t)i * 8);
  const float4 f1 = *reinterpret_cast<const float4*>(x + (size_t)i * 8 + 4);
  bf16x8 v;
  v[0] = (bf16)f0.x; v[1] = (bf16)f0.y; v[2] = (bf16)f0.z; v[3] = (bf16)f0.w;
  v[4] = (bf16)f1.x; v[5] = (bf16)f1.y; v[6] = (bf16)f1.z; v[7] = (bf16)f1.w;
  const int row = b * NPAT + (h >> 4) * 14 + (w8 >> 1);
  const int k = c * 256 + (h & 15) * 16 + (w8 & 1) * 8;
  *reinterpret_cast<bf16x8*>(A + (size_t)row * KDIM + k) = v;
}

// ---------------------------------------------------------------------------
// Kernel 3: main GEMM (m97 structure): C[row][e] = sum_k A[row][k]*Wb[e][k]
// 128x128 tile, 4 waves of 64x64, BK=32, global_load_lds width-16 staging,
// linear LDS [128][32]. Epilogue adds proj_b + pos_emb, scatters past cls row.
// ---------------------------------------------------------------------------
__global__ __launch_bounds__(256) void gemm_lds_kernel(
    const bf16* __restrict__ A, const bf16* __restrict__ Wb,
    const float* __restrict__ pb, const float* __restrict__ pos,
    float* __restrict__ out) {
  __shared__ __align__(16) bf16 sA[128 * 32];
  __shared__ __align__(16) bf16 sB[128 * 32];

  const int nt = blockIdx.x;  // 0..5
  const int mt = blockIdx.y;  // 0..195
  const int t = threadIdx.x;
  const int l = t & 63;
  const int wv = t >> 6;
  const int wm = wv >> 1, wn = wv & 1;

  // staging: thread t covers bytes [t*16, t*16+16) of each 4KB half-tile
  const bf16* gA0 = A + ((size_t)(mt * 128) + (t >> 2)) * KDIM + (t & 3) * 8;
  const bf16* gA1 = gA0 + (size_t)64 * KDIM;
  const bf16* gB0 = Wb + ((size_t)(nt * 128) + (t >> 2)) * KDIM + (t & 3) * 8;
  const bf16* gB1 = gB0 + (size_t)64 * KDIM;
  bf16* lA0 = sA + wv * 512;         // wave-uniform bases; HW adds lane*16B
  bf16* lA1 = sA + 2048 + wv * 512;
  bf16* lB0 = sB + wv * 512;
  bf16* lB1 = sB + 2048 + wv * 512;

  floatx4 acc[4][4];
#pragma unroll
  for (int i = 0; i < 4; ++i)
#pragma unroll
    for (int j = 0; j < 4; ++j) acc[i][j] = (floatx4){0.f, 0.f, 0.f, 0.f};

  const int lr = l & 15;
  const int lk = (l >> 4) * 8;  // k-element offset of this lane's frag

  for (int kt = 0; kt < 24; ++kt) {
    const int ko = kt * 32;
    __syncthreads();  // previous iteration's ds_reads complete
    gload16(gA0 + ko, lA0);
    gload16(gA1 + ko, lA1);
    gload16(gB0 + ko, lB0);
    gload16(gB1 + ko, lB1);
    __syncthreads();  // compiler drains vmcnt(0) before this barrier

    bf16x8 af[4], bfr[4];
#pragma unroll
    for (int mi = 0; mi < 4; ++mi)
      af[mi] = *reinterpret_cast<const bf16x8*>(
          &sA[(wm * 64 + mi * 16 + lr) * 32 + lk]);
#pragma unroll
    for (int ni = 0; ni < 4; ++ni)
      bfr[ni] = *reinterpret_cast<const bf16x8*>(
          &sB[(wn * 64 + ni * 16 + lr) * 32 + lk]);
#pragma unroll
    for (int mi = 0; mi < 4; ++mi)
#pragma unroll
      for (int ni = 0; ni < 4; ++ni)
        acc[mi][ni] = __builtin_amdgcn_mfma_f32_16x16x32_bf16(
            af[mi], bfr[ni], acc[mi][ni], 0, 0, 0);
  }

  // epilogue: out[b][1+n][e] = acc + proj_b[e] + pos_emb[1+n][e]
  float pbv[4];
#pragma unroll
  for (int ni = 0; ni < 4; ++ni)
    pbv[ni] = pb[nt * 128 + wn * 64 + ni * 16 + (l & 15)];

#pragma unroll
  for (int mi = 0; mi < 4; ++mi) {
#pragma unroll
    for (int j = 0; j < 4; ++j) {
      const unsigned m = wm * 64 + mi * 16 + ((l >> 4) << 2) + j;
      const unsigned Rr = mt * 128u + m;
      const unsigned b2 = Rr / 196u;
      const unsigned np2 = Rr - b2 * 196u;
      float* orow = out + ((size_t)b2 * 197 + 1 + np2) * 768;
      const float* prow = pos + (size_t)(1 + np2) * 768;
#pragma unroll
      for (int ni = 0; ni < 4; ++ni) {
        const int e = nt * 128 + wn * 64 + ni * 16 + (l & 15);
        orow[e] = acc[mi][ni][j] + pbv[ni] + prow[e];
      }
    }
  }
}

// ---------------------------------------------------------------------------
// Fallback GEMM (round-1, passed): used only if ws_size can't hold A.
// ---------------------------------------------------------------------------
__global__ __launch_bounds__(256) void gemm_fallback(
    const float* __restrict__ x, const bf16* __restrict__ Wb,
    const float* __restrict__ pb, const float* __restrict__ pos,
    float* __restrict__ out) {
  __shared__ __align__(16) bf16 sA[128 * LDT];
  __shared__ __align__(16) bf16 sB[128 * LDT];
  const int nt = blockIdx.x;
  const int mt = blockIdx.y;
  const int t = threadIdx.x;
  const int l = t & 63;
  const int wv = t >> 6;
  const int wm = wv >> 1, wn = wv & 1;
  const int sr = t >> 1;
  const int half = t & 1;
  const unsigned R = mt * 128u + sr;
  const unsigned bb = R / 196u;
  const unsigned np = R - bb * 196u;
  const unsigned ph = np / 14u;
  const unsigned pwc = np - ph * 14u;
  const int eRow = nt * 128 + sr;
  floatx4 acc[4][4];
#pragma unroll
  for (int i = 0; i < 4; ++i)
#pragma unroll
    for (int j = 0; j < 4; ++j) acc[i][j] = (floatx4){0.f, 0.f, 0.f, 0.f};
  const int lk = (l >> 4) << 3;
  const int lr = l & 15;
  for (int kt = 0; kt < 24; ++kt) {
    const int kg = kt * 32 + half * 16;
    const int c = kg >> 8;
    const int hh = (kg & 255) >> 4;
    const float* src =
        x + (((size_t)(bb * 3u + c) * 224u + ph * 16u + hh) * 224u + pwc * 16u);
    const float4 f0 = *reinterpret_cast<const float4*>(src + 0);
    const float4 f1 = *reinterpret_cast<const float4*>(src + 4);
    const float4 f2 = *reinterpret_cast<const float4*>(src + 8);
    const float4 f3 = *reinterpret_cast<const float4*>(src + 12);
    bf16x8 a0, a1;
    a0[0] = (bf16)f0.x; a0[1] = (bf16)f0.y; a0[2] = (bf16)f0.z; a0[3] = (bf16)f0.w;
    a0[4] = (bf16)f1.x; a0[5] = (bf16)f1.y; a0[6] = (bf16)f1.z; a0[7] = (bf16)f1.w;
    a1[0] = (bf16)f2.x; a1[1] = (bf16)f2.y; a1[2] = (bf16)f2.z; a1[3] = (bf16)f2.w;
    a1[4] = (bf16)f3.x; a1[5] = (bf16)f3.y; a1[6] = (bf16)f3.z; a1[7] = (bf16)f3.w;
    const bf16x8 b0 =
        *reinterpret_cast<const bf16x8*>(Wb + (size_t)eRow * KDIM + kg);
    const bf16x8 b1 =
        *reinterpret_cast<const bf16x8*>(Wb + (size_t)eRow * KDIM + kg + 8);
    __syncthreads();
    *reinterpret_cast<bf16x8*>(&sA[sr * LDT + half * 16]) = a0;
    *reinterpret_cast<bf16x8*>(&sA[sr * LDT + half * 16 + 8]) = a1;
    *reinterpret_cast<bf16x8*>(&sB[sr * LDT + half * 16]) = b0;
    *reinterpret_cast<bf16x8*>(&sB[sr * LDT + half * 16 + 8]) = b1;
    __syncthreads();
    bf16x8 af[4], bfr[4];
#pragma unroll
    for (int mi = 0; mi < 4; ++mi)
      af[mi] = *reinterpret_cast<const bf16x8*>(
          &sA[(wm * 64 + mi * 16 + lr) * LDT + lk]);
#pragma unroll
    for (int ni = 0; ni < 4; ++ni)
      bfr[ni] = *reinterpret_cast<const bf16x8*>(
          &sB[(wn * 64 + ni * 16 + lr) * LDT + lk]);
#pragma unroll
    for (int mi = 0; mi < 4; ++mi)
#pragma unroll
      for (int ni = 0; ni < 4; ++ni)
        acc[mi][ni] = __builtin_amdgcn_mfma_f32_16x16x32_bf16(
            af[mi], bfr[ni], acc[mi][ni], 0, 0, 0);
  }
  float pbv[4];
#pragma unroll
  for (int ni = 0; ni < 4; ++ni)
    pbv[ni] = pb[nt * 128 + wn * 64 + ni * 16 + (l & 15)];
#pragma unroll
  for (int mi = 0; mi < 4; ++mi) {
#pragma unroll
    for (int j = 0; j < 4; ++j) {
      const unsigned m = wm * 64 + mi * 16 + ((l >> 4) << 2) + j;
      const unsigned Rr = mt * 128u + m;
      const unsigned b2 = Rr / 196u;
      const unsigned np2 = Rr - b2 * 196u;
      float* orow = out + ((size_t)b2 * 197 + 1 + np2) * 768;
      const float* prow = pos + (size_t)(1 + np2) * 768;
#pragma unroll
      for (int ni = 0; ni < 4; ++ni) {
        const int e = nt * 128 + wn * 64 + ni * 16 + (l & 15);
        orow[e] = acc[mi][ni][j] + pbv[ni] + prow[e];
      }
    }
  }
}

// ---------------------------------------------------------------------------
// Kernel 4: cls row  out[b][0][e] = cls[e] + pos_emb[0][e]
// ---------------------------------------------------------------------------
__global__ __launch_bounds__(256) void cls_kernel(
    const float* __restrict__ cls, const float* __restrict__ pos,
    float* __restrict__ out) {
  const int idx = blockIdx.x * 256 + threadIdx.x;
  const int b = idx / 768;
  const int e = idx - b * 768;
  out[(size_t)b * 197 * 768 + e] = cls[e] + pos[e];
}

extern "C" void kernel_launch(void* const* d_in, const int* in_sizes, int n_in,
                              void* d_out, int out_size, void* d_ws,
                              size_t ws_size, hipStream_t stream) {
  const float* x = (const float*)d_in[0];
  const float* fwh = (const float*)d_in[1];
  const float* fww = (const float*)d_in[2];
  const float* proj_w = (const float*)d_in[3];
  const float* proj_b = (const float*)d_in[4];
  const float* cls = (const float*)d_in[5];
  const float* pos = (const float*)d_in[6];
  float* out = (float*)d_out;

  const size_t needW = (size_t)EDIM * KDIM * sizeof(bf16);      // 1.18 MB
  const size_t needA = (size_t)MROWS * KDIM * sizeof(bf16);     // 38.5 MB
  bf16* Wb = (bf16*)d_ws;

  build_w_kernel<<<EDIM * 3, 256, 0, stream>>>(proj_w, fwh, fww, Wb);
  cls_kernel<<<(NBATCH * EDIM) / 256, 256, 0, stream>>>(cls, pos, out);

  if (ws_size >= needW + needA) {
    bf16* A = (bf16*)((char*)d_ws + needW);
    unfold_kernel<<<(MROWS * KDIM / 8) / 256, 256, 0, stream>>>(x, A);
    gemm_lds_kernel<<<dim3(6, 196), 256, 0, stream>>>(A, Wb, proj_b, pos, out);
  } else {
    gemm_fallback<<<dim3(6, 196), 256, 0, stream>>>(x, Wb, proj_b, pos, out);
  }
}

// Round 3
// 95.145 us; speedup vs baseline: 1.2037x; 1.0421x over previous
//
#include <hip/hip_runtime.h>
#include <hip/hip_bf16.h>

typedef __bf16 bf16;
typedef __attribute__((ext_vector_type(8))) __bf16 bf16x8;
typedef __attribute__((ext_vector_type(4))) float floatx4;

#define PP 16
#define PPW 9
#define CFEAT 432      // C*P*PW = 3*16*9
#define EDIM 768
#define KDIM 768       // C*P*P = 3*256
#define NPAT 196
#define NBATCH 128
#define MROWS (NBATCH * NPAT)  // 25088
#define LDT 40         // fallback-path padded LDS stride

__device__ inline void gload16(const void* g, void* l) {
  __builtin_amdgcn_global_load_lds(
      (const __attribute__((address_space(1))) void*)g,
      (__attribute__((address_space(3))) void*)l, 16, 0, 0);
}

// ---------------------------------------------------------------------------
// Kernel 1: fold rfft2(ortho).real * fwh * fww into proj_w -> W_eff (bf16)
// ---------------------------------------------------------------------------
__global__ __launch_bounds__(256) void build_w_kernel(
    const float* __restrict__ pw, const float* __restrict__ fwh,
    const float* __restrict__ fww, bf16* __restrict__ Wb) {
  __shared__ float s_pw[144];
  __shared__ float s_fh[16];
  __shared__ float s_fw[9];
  __shared__ float s_cos[16];
  const int blk = blockIdx.x;
  const int e = blk / 3;
  const int c = blk % 3;
  const int t = threadIdx.x;
  if (t < 144) s_pw[t] = pw[e * CFEAT + c * 144 + t];
  if (t < 16) {
    s_fh[t] = fwh[t];
    s_cos[t] = cosf((float)t * 0.39269908169872414f);  // 2*pi/16
  }
  if (t < 9) s_fw[t] = fww[t];
  __syncthreads();
  const int h = t >> 4, w = t & 15;
  float acc = 0.f;
#pragma unroll
  for (int u = 0; u < 16; ++u) {
    const float fh = s_fh[u];
    const int uh = (u * h) & 15;
#pragma unroll
    for (int v = 0; v < 9; ++v) {
      acc += s_pw[u * 9 + v] * s_fw[v] * s_cos[(uh + v * w) & 15] * fh;
    }
  }
  Wb[e * KDIM + c * 256 + t] = (bf16)(acc * 0.0625f);
}

// ---------------------------------------------------------------------------
// Kernel 2: patch-unfold + fp32->bf16:  A[b*196+n][c*256+h2*16+w2] = x[b][c][h][w]
// ---------------------------------------------------------------------------
__global__ __launch_bounds__(256) void unfold_kernel(
    const float* __restrict__ x, bf16* __restrict__ A) {
  const int i = blockIdx.x * 256 + threadIdx.x;  // < 2408448
  const int w8 = i % 28;
  const int tmp = i / 28;
  const int h = tmp % 224;
  const int tmp2 = tmp / 224;
  const int c = tmp2 % 3;
  const int b = tmp2 / 3;
  const float4 f0 = *reinterpret_cast<const float4*>(x + (size_t)i * 8);
  const float4 f1 = *reinterpret_cast<const float4*>(x + (size_t)i * 8 + 4);
  bf16x8 v;
  v[0] = (bf16)f0.x; v[1] = (bf16)f0.y; v[2] = (bf16)f0.z; v[3] = (bf16)f0.w;
  v[4] = (bf16)f1.x; v[5] = (bf16)f1.y; v[6] = (bf16)f1.z; v[7] = (bf16)f1.w;
  const int row = b * NPAT + (h >> 4) * 14 + (w8 >> 1);
  const int k = c * 256 + (h & 15) * 16 + (w8 & 1) * 8;
  *reinterpret_cast<bf16x8*>(A + (size_t)row * KDIM + k) = v;
}

// ---------------------------------------------------------------------------
// Kernel 3: main GEMM, double-buffered prefetch (T3 minimum 2-phase recipe):
//   per iter: STAGE(buf^1, kt+1) -> ds_read+MFMA on buf -> ONE barrier
// (vmcnt(0) drain at the barrier lands AFTER compute -> load latency hidden).
// 128x128 tile, 4 waves of 64x64, BK=32, global_load_lds width-16 staging.
// ---------------------------------------------------------------------------
__global__ __launch_bounds__(256) void gemm_db_kernel(
    const bf16* __restrict__ A, const bf16* __restrict__ Wb,
    const float* __restrict__ pb, const float* __restrict__ pos,
    float* __restrict__ out) {
  __shared__ __align__(16) bf16 sA[2][128 * 32];
  __shared__ __align__(16) bf16 sB[2][128 * 32];

  const int nt = blockIdx.x;  // 0..5
  const int mt = blockIdx.y;  // 0..195
  const int t = threadIdx.x;
  const int l = t & 63;
  const int wv = t >> 6;
  const int wm = wv >> 1, wn = wv & 1;

  // staging: thread t covers bytes [t*16, t*16+16) of each 4KB half-tile
  const bf16* gA = A + ((size_t)(mt * 128) + (t >> 2)) * KDIM + (t & 3) * 8;
  const bf16* gB = Wb + ((size_t)(nt * 128) + (t >> 2)) * KDIM + (t & 3) * 8;
  const size_t rstep = (size_t)64 * KDIM;
  const int lbase = wv * 512;  // wave-uniform LDS base (elems); HW adds lane*16B

#define STAGE(buf, ko)                                  \
  do {                                                  \
    gload16(gA + (ko), &sA[buf][lbase]);                \
    gload16(gA + rstep + (ko), &sA[buf][2048 + lbase]); \
    gload16(gB + (ko), &sB[buf][lbase]);                \
    gload16(gB + rstep + (ko), &sB[buf][2048 + lbase]); \
  } while (0)

  floatx4 acc[4][4];
#pragma unroll
  for (int i = 0; i < 4; ++i)
#pragma unroll
    for (int j = 0; j < 4; ++j) acc[i][j] = (floatx4){0.f, 0.f, 0.f, 0.f};

  const int lr = l & 15;
  const int lk = (l >> 4) * 8;  // k-element offset of this lane's frag

#define COMPUTE(buf)                                              \
  do {                                                            \
    bf16x8 af[4], bfr[4];                                         \
    _Pragma("unroll") for (int mi = 0; mi < 4; ++mi) af[mi] =     \
        *reinterpret_cast<const bf16x8*>(                         \
            &sA[buf][(wm * 64 + mi * 16 + lr) * 32 + lk]);        \
    _Pragma("unroll") for (int ni = 0; ni < 4; ++ni) bfr[ni] =    \
        *reinterpret_cast<const bf16x8*>(                         \
            &sB[buf][(wn * 64 + ni * 16 + lr) * 32 + lk]);        \
    _Pragma("unroll") for (int mi = 0; mi < 4; ++mi)              \
        _Pragma("unroll") for (int ni = 0; ni < 4; ++ni) acc[mi]  \
            [ni] = __builtin_amdgcn_mfma_f32_16x16x32_bf16(       \
                af[mi], bfr[ni], acc[mi][ni], 0, 0, 0);           \
  } while (0)

  STAGE(0, 0);
  __syncthreads();
  int cur = 0;
  for (int kt = 0; kt < 23; ++kt) {
    STAGE(cur ^ 1, (kt + 1) * 32);  // prefetch next tile (in flight thru compute)
    COMPUTE(cur);
    __syncthreads();  // vmcnt(0)+lgkmcnt(0) drain AFTER compute
    cur ^= 1;
  }
  COMPUTE(cur);
#undef STAGE
#undef COMPUTE

  // epilogue: out[b][1+n][e] = acc + proj_b[e] + pos_emb[1+n][e]
  float pbv[4];
#pragma unroll
  for (int ni = 0; ni < 4; ++ni)
    pbv[ni] = pb[nt * 128 + wn * 64 + ni * 16 + (l & 15)];

#pragma unroll
  for (int mi = 0; mi < 4; ++mi) {
#pragma unroll
    for (int j = 0; j < 4; ++j) {
      const unsigned m = wm * 64 + mi * 16 + ((l >> 4) << 2) + j;
      const unsigned Rr = mt * 128u + m;
      const unsigned b2 = Rr / 196u;
      const unsigned np2 = Rr - b2 * 196u;
      float* orow = out + ((size_t)b2 * 197 + 1 + np2) * 768;
      const float* prow = pos + (size_t)(1 + np2) * 768;
#pragma unroll
      for (int ni = 0; ni < 4; ++ni) {
        const int e = nt * 128 + wn * 64 + ni * 16 + (l & 15);
        orow[e] = acc[mi][ni][j] + pbv[ni] + prow[e];
      }
    }
  }
}

// ---------------------------------------------------------------------------
// Fallback GEMM (round-1, passed): used only if ws_size can't hold A.
// ---------------------------------------------------------------------------
__global__ __launch_bounds__(256) void gemm_fallback(
    const float* __restrict__ x, const bf16* __restrict__ Wb,
    const float* __restrict__ pb, const float* __restrict__ pos,
    float* __restrict__ out) {
  __shared__ __align__(16) bf16 sA[128 * LDT];
  __shared__ __align__(16) bf16 sB[128 * LDT];
  const int nt = blockIdx.x;
  const int mt = blockIdx.y;
  const int t = threadIdx.x;
  const int l = t & 63;
  const int wv = t >> 6;
  const int wm = wv >> 1, wn = wv & 1;
  const int sr = t >> 1;
  const int half = t & 1;
  const unsigned R = mt * 128u + sr;
  const unsigned bb = R / 196u;
  const unsigned np = R - bb * 196u;
  const unsigned ph = np / 14u;
  const unsigned pwc = np - ph * 14u;
  const int eRow = nt * 128 + sr;
  floatx4 acc[4][4];
#pragma unroll
  for (int i = 0; i < 4; ++i)
#pragma unroll
    for (int j = 0; j < 4; ++j) acc[i][j] = (floatx4){0.f, 0.f, 0.f, 0.f};
  const int lk = (l >> 4) << 3;
  const int lr = l & 15;
  for (int kt = 0; kt < 24; ++kt) {
    const int kg = kt * 32 + half * 16;
    const int c = kg >> 8;
    const int hh = (kg & 255) >> 4;
    const float* src =
        x + (((size_t)(bb * 3u + c) * 224u + ph * 16u + hh) * 224u + pwc * 16u);
    const float4 f0 = *reinterpret_cast<const float4*>(src + 0);
    const float4 f1 = *reinterpret_cast<const float4*>(src + 4);
    const float4 f2 = *reinterpret_cast<const float4*>(src + 8);
    const float4 f3 = *reinterpret_cast<const float4*>(src + 12);
    bf16x8 a0, a1;
    a0[0] = (bf16)f0.x; a0[1] = (bf16)f0.y; a0[2] = (bf16)f0.z; a0[3] = (bf16)f0.w;
    a0[4] = (bf16)f1.x; a0[5] = (bf16)f1.y; a0[6] = (bf16)f1.z; a0[7] = (bf16)f1.w;
    a1[0] = (bf16)f2.x; a1[1] = (bf16)f2.y; a1[2] = (bf16)f2.z; a1[3] = (bf16)f2.w;
    a1[4] = (bf16)f3.x; a1[5] = (bf16)f3.y; a1[6] = (bf16)f3.z; a1[7] = (bf16)f3.w;
    const bf16x8 b0 =
        *reinterpret_cast<const bf16x8*>(Wb + (size_t)eRow * KDIM + kg);
    const bf16x8 b1 =
        *reinterpret_cast<const bf16x8*>(Wb + (size_t)eRow * KDIM + kg + 8);
    __syncthreads();
    *reinterpret_cast<bf16x8*>(&sA[sr * LDT + half * 16]) = a0;
    *reinterpret_cast<bf16x8*>(&sA[sr * LDT + half * 16 + 8]) = a1;
    *reinterpret_cast<bf16x8*>(&sB[sr * LDT + half * 16]) = b0;
    *reinterpret_cast<bf16x8*>(&sB[sr * LDT + half * 16 + 8]) = b1;
    __syncthreads();
    bf16x8 af[4], bfr[4];
#pragma unroll
    for (int mi = 0; mi < 4; ++mi)
      af[mi] = *reinterpret_cast<const bf16x8*>(
          &sA[(wm * 64 + mi * 16 + lr) * LDT + lk]);
#pragma unroll
    for (int ni = 0; ni < 4; ++ni)
      bfr[ni] = *reinterpret_cast<const bf16x8*>(
          &sB[(wn * 64 + ni * 16 + lr) * LDT + lk]);
#pragma unroll
    for (int mi = 0; mi < 4; ++mi)
#pragma unroll
      for (int ni = 0; ni < 4; ++ni)
        acc[mi][ni] = __builtin_amdgcn_mfma_f32_16x16x32_bf16(
            af[mi], bfr[ni], acc[mi][ni], 0, 0, 0);
  }
  float pbv[4];
#pragma unroll
  for (int ni = 0; ni < 4; ++ni)
    pbv[ni] = pb[nt * 128 + wn * 64 + ni * 16 + (l & 15)];
#pragma unroll
  for (int mi = 0; mi < 4; ++mi) {
#pragma unroll
    for (int j = 0; j < 4; ++j) {
      const unsigned m = wm * 64 + mi * 16 + ((l >> 4) << 2) + j;
      const unsigned Rr = mt * 128u + m;
      const unsigned b2 = Rr / 196u;
      const unsigned np2 = Rr - b2 * 196u;
      float* orow = out + ((size_t)b2 * 197 + 1 + np2) * 768;
      const float* prow = pos + (size_t)(1 + np2) * 768;
#pragma unroll
      for (int ni = 0; ni < 4; ++ni) {
        const int e = nt * 128 + wn * 64 + ni * 16 + (l & 15);
        orow[e] = acc[mi][ni][j] + pbv[ni] + prow[e];
      }
    }
  }
}

// ---------------------------------------------------------------------------
// Kernel 4: cls row  out[b][0][e] = cls[e] + pos_emb[0][e]
// ---------------------------------------------------------------------------
__global__ __launch_bounds__(256) void cls_kernel(
    const float* __restrict__ cls, const float* __restrict__ pos,
    float* __restrict__ out) {
  const int idx = blockIdx.x * 256 + threadIdx.x;
  const int b = idx / 768;
  const int e = idx - b * 768;
  out[(size_t)b * 197 * 768 + e] = cls[e] + pos[e];
}

extern "C" void kernel_launch(void* const* d_in, const int* in_sizes, int n_in,
                              void* d_out, int out_size, void* d_ws,
                              size_t ws_size, hipStream_t stream) {
  const float* x = (const float*)d_in[0];
  const float* fwh = (const float*)d_in[1];
  const float* fww = (const float*)d_in[2];
  const float* proj_w = (const float*)d_in[3];
  const float* proj_b = (const float*)d_in[4];
  const float* cls = (const float*)d_in[5];
  const float* pos = (const float*)d_in[6];
  float* out = (float*)d_out;

  const size_t needW = (size_t)EDIM * KDIM * sizeof(bf16);      // 1.18 MB
  const size_t needA = (size_t)MROWS * KDIM * sizeof(bf16);     // 38.5 MB
  bf16* Wb = (bf16*)d_ws;

  build_w_kernel<<<EDIM * 3, 256, 0, stream>>>(proj_w, fwh, fww, Wb);
  cls_kernel<<<(NBATCH * EDIM) / 256, 256, 0, stream>>>(cls, pos, out);

  if (ws_size >= needW + needA) {
    bf16* A = (bf16*)((char*)d_ws + needW);
    unfold_kernel<<<(MROWS * KDIM / 8) / 256, 256, 0, stream>>>(x, A);
    gemm_db_kernel<<<dim3(6, 196), 256, 0, stream>>>(A, Wb, proj_b, pos, out);
  } else {
    gemm_fallback<<<dim3(6, 196), 256, 0, stream>>>(x, Wb, proj_b, pos, out);
  }
}